// Round 1
// baseline (237.206 us; speedup 1.0000x reference)
//
#include <hip/hip_runtime.h>

// ---------------- problem constants ----------------
#define NF   12
#define NN   4
#define DD   8
#define NDIM 32
#define NCLS 3

// TEMP = max(sqrt(8)*0.3, 0.5)
#define INV_TEMP 1.1785113019775793f

// ---------------- ws layout (floats) ----------------
#define WS_ACC 0    // double accumulator (2 floats)
#define WS_WE2 2    // 384  folded embed (adj folded in)
#define WS_BE2 386  // 32   folded embed bias
#define WS_H1C 418  // 16   homeo layer-1 constant part
#define WS_QK  434  // 16   qk[r*8+d] = sum_e q_w[d][e]*K[r][e]
#define WS_QB  450  // 2    qb[r] = q_b . K[r]
#define WS_WOT 452  // 96   W_out transposed [3][32]

// ---------------- helpers ----------------
__device__ __forceinline__ float fsig(float x)   { return 1.0f/(1.0f+__expf(-x)); }
__device__ __forceinline__ float ftanh_(float x) { return 2.0f/(1.0f+__expf(-2.0f*x)) - 1.0f; }
__device__ __forceinline__ float fclip(float v,float lo,float hi){ return fminf(fmaxf(v,lo),hi); }
__device__ __forceinline__ void  fma4(float4&a,const float4&b,float s){ a.x+=b.x*s; a.y+=b.y*s; a.z+=b.z*s; a.w+=b.w*s; }
__device__ __forceinline__ float dot4(const float4&a,const float4&b){ return a.x*b.x+a.y*b.y+a.z*b.z+a.w*b.w; }
__device__ __forceinline__ float hsum4(const float4&a){ return a.x+a.y+a.z+a.w; }
__device__ __forceinline__ float4 clip4(float4 a,float lo,float hi){
  a.x=fclip(a.x,lo,hi); a.y=fclip(a.y,lo,hi); a.z=fclip(a.z,lo,hi); a.w=fclip(a.w,lo,hi); return a;
}

// ---------------- setup: fold constants into ws ----------------
__global__ void setup_k(const float* __restrict__ We,  const float* __restrict__ be,
                        const float* __restrict__ adjw,const float* __restrict__ Ww,
                        const float* __restrict__ w1,  const float* __restrict__ b1,
                        const float* __restrict__ basis,const float* __restrict__ qw,
                        const float* __restrict__ qb,  const float* __restrict__ kw,
                        const float* __restrict__ kb,  const float* __restrict__ Wo,
                        float* __restrict__ ws)
{
  __shared__ float adj[16];
  __shared__ float K[16];
  const int t = threadIdx.x;
  if (t == 0) {
    // 2x2 grid mask, row-normalized sigmoid adjacency
    const int mb[16] = {0,1,1,0, 1,0,0,1, 1,0,0,1, 0,1,1,0};
    for (int i=0;i<4;i++){
      float r[4]; float s=0.f;
      for (int j=0;j<4;j++){ float a = mb[i*4+j] ? fsig(adjw[i*4+j]) : 0.f; r[j]=a; s+=a; }
      s = fmaxf(s, 1e-6f);
      for (int j=0;j<4;j++) adj[i*4+j] = r[j]/s;
    }
    *reinterpret_cast<double*>(ws + WS_ACC) = 0.0;   // zero gate accumulator
  }
  __syncthreads();
  // folded embed: WE2[f][i*8+d] = sum_j adj[i][j]*We[f][j*8+d]
  for (int idx=t; idx<384; idx+=blockDim.x){
    int f=idx>>5, od=idx&31, i=od>>3, d=od&7;
    float s=0.f;
    for (int j=0;j<4;j++) s += adj[i*4+j]*We[f*32 + j*8 + d];
    ws[WS_WE2+idx]=s;
  }
  for (int idx=t; idx<32; idx+=blockDim.x){
    int i=idx>>3, d=idx&7;
    float s=0.f;
    for (int j=0;j<4;j++) s += adj[i*4+j]*be[j*8 + d];
    ws[WS_BE2+idx]=s;
  }
  // homeo layer-1 constant: cf*w1[2,:] + 0.5*w1[3,:] + b1
  if (t < 16){
    float s2=0.f;
    for (int k=0;k<64;k++) s2 += Ww[k]*Ww[k];
    float cf = sqrtf(s2);
    ws[WS_H1C+t] = cf*w1[32+t] + 0.5f*w1[48+t] + b1[t];
  }
  // K = basis @ k_w + k_b   [2,8]
  if (t < 16){
    int r=t>>3, e=t&7;
    float s=kb[e];
    for (int d=0;d<8;d++) s += basis[r*8+d]*kw[d*8+e];
    K[t]=s;
  }
  __syncthreads();
  // qk[r][d] = sum_e q_w[d][e]*K[r][e] ;  qb[r] = q_b . K[r]
  if (t < 16){
    int r=t>>3, d=t&7;
    float s=0.f;
    for (int e=0;e<8;e++) s += qw[d*8+e]*K[r*8+e];
    ws[WS_QK+t]=s;
  }
  if (t < 2){
    float s=0.f;
    for (int e=0;e<8;e++) s += qb[e]*K[t*8+e];
    ws[WS_QB+t]=s;
  }
  // W_out transposed: woT[c][od]
  for (int idx=t; idx<96; idx+=blockDim.x){
    int c=idx/32, od=idx%32;
    ws[WS_WOT+idx]=Wo[od*3+c];
  }
}

// ---------------- pass 1: gate_value reduction ----------------
__global__ __launch_bounds__(256) void pass1_k(
    const float* __restrict__ x,  const float* __restrict__ ws,
    const float* __restrict__ Ww, const float* __restrict__ w1,
    const float* __restrict__ g,  const float* __restrict__ be,
    const float* __restrict__ w2, const float* __restrict__ b2,
    const float* __restrict__ aw, const float* __restrict__ ab,
    double* __restrict__ acc, int nB)
{
  __shared__ float4 sWE4[96];
  __shared__ float4 sBE4[8];
  __shared__ float4 sWw4[16];
  __shared__ float4 sW1a4[4], sW1b4[4], sH1C4[4], sG4[4], sBe4[4];
  __shared__ float4 sW24[32];
  __shared__ float  sAw[8], sB2[8], sAb;
  __shared__ double wsum[4];
  const int t = threadIdx.x;
  { float* p;
    p=(float*)sWE4;  for (int i=t;i<384;i+=256) p[i]=ws[WS_WE2+i];
    p=(float*)sBE4;  if (t<32) p[t]=ws[WS_BE2+t];
    p=(float*)sWw4;  if (t<64) p[t]=Ww[t];
    p=(float*)sW1a4; if (t<16) p[t]=w1[t];
    p=(float*)sW1b4; if (t<16) p[t]=w1[16+t];
    p=(float*)sH1C4; if (t<16) p[t]=ws[WS_H1C+t];
    p=(float*)sG4;   if (t<16) p[t]=g[t];
    p=(float*)sBe4;  if (t<16) p[t]=be[t];
    p=(float*)sW24;  for (int i=t;i<128;i+=256) p[i]=w2[i];
    if (t<8){ sAw[t]=aw[t*4+2]; sB2[t]=b2[t]; }
    if (t==0) sAb=ab[2];
  }
  __syncthreads();

  float csum = 0.f;
  const int b = blockIdx.x*256 + t;
  if (b < nB) {
    const float4* xp = reinterpret_cast<const float4*>(x + (size_t)b*NF);
    float4 xa=xp[0], xb=xp[1], xc=xp[2];
    const float xv[12] = {xa.x,xa.y,xa.z,xa.w, xb.x,xb.y,xb.z,xb.w, xc.x,xc.y,xc.z,xc.w};
    // h = x @ WE2 + BE2   (32 outputs as 8 float4)
    float4 h4[8];
    #pragma unroll
    for (int o=0;o<8;o++) h4[o]=sBE4[o];
    #pragma unroll
    for (int f=0;f<12;f++){
      #pragma unroll
      for (int o=0;o<8;o++) fma4(h4[o], sWE4[f*8+o], xv[f]);
    }
    #pragma unroll
    for (int i=0;i<4;i++){
      const float4 r0=h4[2*i], r1=h4[2*i+1];
      const float hr[8] = {r0.x,r0.y,r0.z,r0.w, r1.x,r1.y,r1.z,r1.w};
      // surprise = |var(h_row) - 0.5|
      float mu = (hsum4(r0)+hsum4(r1))*0.125f;
      float m2 = 0.f;
      #pragma unroll
      for (int d=0;d<8;d++){ float dd=hr[d]-mu; m2+=dd*dd; }
      const float surprise = fabsf(m2*0.125f - 0.5f);
      // excitation = mean|h @ Ww|
      float4 e0={0,0,0,0}, e1={0,0,0,0};
      #pragma unroll
      for (int d=0;d<8;d++){ fma4(e0,sWw4[d*2],hr[d]); fma4(e1,sWw4[d*2+1],hr[d]); }
      const float exc = (fabsf(e0.x)+fabsf(e0.y)+fabsf(e0.z)+fabsf(e0.w)
                        +fabsf(e1.x)+fabsf(e1.y)+fabsf(e1.z)+fabsf(e1.w))*0.125f;
      // homeo layer 1 + LN + tanh
      float4 h1q[4]; float hmu=0.f;
      #pragma unroll
      for (int q=0;q<4;q++){
        float4 v = sH1C4[q];
        fma4(v, sW1a4[q], surprise);
        fma4(v, sW1b4[q], exc);
        h1q[q]=v; hmu += hsum4(v);
      }
      hmu *= 0.0625f;
      float hvar=0.f;
      #pragma unroll
      for (int q=0;q<4;q++){
        float dx=h1q[q].x-hmu, dy=h1q[q].y-hmu, dz=h1q[q].z-hmu, dw=h1q[q].w-hmu;
        hvar += dx*dx+dy*dy+dz*dz+dw*dw;
      }
      hvar *= 0.0625f;
      const float rs = rsqrtf(hvar + 1e-5f);
      float ht[16];
      #pragma unroll
      for (int q=0;q<4;q++){
        ht[q*4+0]=ftanh_((h1q[q].x-hmu)*rs*sG4[q].x + sBe4[q].x);
        ht[q*4+1]=ftanh_((h1q[q].y-hmu)*rs*sG4[q].y + sBe4[q].y);
        ht[q*4+2]=ftanh_((h1q[q].z-hmu)*rs*sG4[q].z + sBe4[q].z);
        ht[q*4+3]=ftanh_((h1q[q].w-hmu)*rs*sG4[q].w + sBe4[q].w);
      }
      // layer 2 (relu) then only column 2 of layer 3
      float4 a0={0,0,0,0}, a1={0,0,0,0};
      #pragma unroll
      for (int k=0;k<16;k++){ fma4(a0,sW24[k*2],ht[k]); fma4(a1,sW24[k*2+1],ht[k]); }
      float ctl = sAb;
      ctl += fmaxf(a0.x+sB2[0],0.f)*sAw[0];
      ctl += fmaxf(a0.y+sB2[1],0.f)*sAw[1];
      ctl += fmaxf(a0.z+sB2[2],0.f)*sAw[2];
      ctl += fmaxf(a0.w+sB2[3],0.f)*sAw[3];
      ctl += fmaxf(a1.x+sB2[4],0.f)*sAw[4];
      ctl += fmaxf(a1.y+sB2[5],0.f)*sAw[5];
      ctl += fmaxf(a1.z+sB2[6],0.f)*sAw[6];
      ctl += fmaxf(a1.w+sB2[7],0.f)*sAw[7];
      csum += fsig(ctl);
    }
  }
  // block reduce -> one double atomic per block
  #pragma unroll
  for (int off=32; off>0; off>>=1) csum += __shfl_down(csum, off, 64);
  if ((t&63)==0) wsum[t>>6] = (double)csum;
  __syncthreads();
  if (t==0) atomicAdd(acc, wsum[0]+wsum[1]+wsum[2]+wsum[3]);
}

// ---------------- pass 2: full forward, write logits ----------------
__global__ __launch_bounds__(256) void pass2_k(
    const float* __restrict__ x,  const float* __restrict__ ws,
    const float* __restrict__ Vw, const float* __restrict__ gw,
    const float* __restrict__ gb, const float* __restrict__ basis,
    const float* __restrict__ bo, const double* __restrict__ acc,
    float* __restrict__ out, int nB)
{
  __shared__ float4 sWE4[96];
  __shared__ float4 sBE4[8];
  __shared__ float4 sVw4[16];
  __shared__ float4 sQk4[4];     // row0: [0..1], row1: [2..3]
  __shared__ float4 sBas4[4];    // basis row0: [0..1], row1: [2..3]
  __shared__ float4 sWoT4[24];   // [3][8] float4
  __shared__ float4 sGw4[2];
  __shared__ float  sGb, sQb[2], sBo[3], sGateVal;
  const int t = threadIdx.x;
  { float* p;
    p=(float*)sWE4;  for (int i=t;i<384;i+=256) p[i]=ws[WS_WE2+i];
    p=(float*)sBE4;  if (t<32) p[t]=ws[WS_BE2+t];
    p=(float*)sVw4;  if (t<64) p[t]=Vw[t];
    p=(float*)sQk4;  if (t<16) p[t]=ws[WS_QK+t];
    p=(float*)sBas4; if (t<16) p[t]=basis[t];
    p=(float*)sWoT4; for (int i=t;i<96;i+=256) p[i]=ws[WS_WOT+i];
    p=(float*)sGw4;  if (t<8) p[t]=gw[t];
    if (t<3) sBo[t]=bo[t];
    if (t==0){
      sGb=gb[0]; sQb[0]=ws[WS_QB]; sQb[1]=ws[WS_QB+1];
      sGateVal = (float)( *acc / (double)(4.0*(double)nB) );
    }
  }
  __syncthreads();

  const int b = blockIdx.x*256 + t;
  if (b >= nB) return;
  const float4* xp = reinterpret_cast<const float4*>(x + (size_t)b*NF);
  float4 xa=xp[0], xb=xp[1], xc=xp[2];
  const float xv[12] = {xa.x,xa.y,xa.z,xa.w, xb.x,xb.y,xb.z,xb.w, xc.x,xc.y,xc.z,xc.w};
  float4 h4[8];
  #pragma unroll
  for (int o=0;o<8;o++) h4[o]=sBE4[o];
  #pragma unroll
  for (int f=0;f<12;f++){
    #pragma unroll
    for (int o=0;o<8;o++) fma4(h4[o], sWE4[f*8+o], xv[f]);
  }
  const float gateVal = sGateVal;
  float4 f4[8];   // flat x_out, 32 floats
  #pragma unroll
  for (int i=0;i<4;i++){
    const float4 r0=h4[2*i], r1=h4[2*i+1];
    const float hr[8] = {r0.x,r0.y,r0.z,r0.w, r1.x,r1.y,r1.z,r1.w};
    // v = clip(h @ Vw)
    float4 v0={0,0,0,0}, v1={0,0,0,0};
    #pragma unroll
    for (int d=0;d<8;d++){ fma4(v0,sVw4[d*2],hr[d]); fma4(v1,sVw4[d*2+1],hr[d]); }
    v0 = clip4(v0,-2.f,2.f); v1 = clip4(v1,-2.f,2.f);
    // gate
    const float gs = sGb + dot4(v0,sGw4[0]) + dot4(v1,sGw4[1]);
    const float gate = fsig(gs)*gateVal;
    float4 c0 = clip4(make_float4(gate*v0.x,gate*v0.y,gate*v0.z,gate*v0.w),-2.f,2.f);
    float4 c1 = clip4(make_float4(gate*v1.x,gate*v1.y,gate*v1.z,gate*v1.w),-2.f,2.f);
    // attention over 2 basis vectors (Q folded)
    float at0 = sQb[0] + dot4(c0,sQk4[0]) + dot4(c1,sQk4[1]);
    float at1 = sQb[1] + dot4(c0,sQk4[2]) + dot4(c1,sQk4[3]);
    at0 = fclip(at0*INV_TEMP,-5.f,5.f);
    at1 = fclip(at1*INV_TEMP,-5.f,5.f);
    const float m  = fmaxf(at0,at1);
    const float e0 = __expf(at0-m), e1 = __expf(at1-m);
    const float w0 = e0/(e0+e1), w1v = 1.f - w0;
    float4 o0, o1;
    o0.x = fclip(w0*sBas4[0].x + w1v*sBas4[2].x + 0.2f*c0.x, -2.f, 2.f);
    o0.y = fclip(w0*sBas4[0].y + w1v*sBas4[2].y + 0.2f*c0.y, -2.f, 2.f);
    o0.z = fclip(w0*sBas4[0].z + w1v*sBas4[2].z + 0.2f*c0.z, -2.f, 2.f);
    o0.w = fclip(w0*sBas4[0].w + w1v*sBas4[2].w + 0.2f*c0.w, -2.f, 2.f);
    o1.x = fclip(w0*sBas4[1].x + w1v*sBas4[3].x + 0.2f*c1.x, -2.f, 2.f);
    o1.y = fclip(w0*sBas4[1].y + w1v*sBas4[3].y + 0.2f*c1.y, -2.f, 2.f);
    o1.z = fclip(w0*sBas4[1].z + w1v*sBas4[3].z + 0.2f*c1.z, -2.f, 2.f);
    o1.w = fclip(w0*sBas4[1].w + w1v*sBas4[3].w + 0.2f*c1.w, -2.f, 2.f);
    f4[2*i]=o0; f4[2*i+1]=o1;
  }
  // readout: out[c] = flat . WoT[c] + bo[c]
  #pragma unroll
  for (int c=0;c<3;c++){
    float s = sBo[c];
    #pragma unroll
    for (int o=0;o<8;o++) s += dot4(f4[o], sWoT4[c*8+o]);
    out[(size_t)b*3+c] = s;
  }
}

// ---------------- launch ----------------
extern "C" void kernel_launch(void* const* d_in, const int* in_sizes, int n_in,
                              void* d_out, int out_size, void* d_ws, size_t ws_size,
                              hipStream_t stream)
{
  const float* x      = (const float*)d_in[0];
  const float* We     = (const float*)d_in[1];
  const float* be_    = (const float*)d_in[2];
  const float* adjw   = (const float*)d_in[3];
  const float* Vw     = (const float*)d_in[4];
  const float* Ww     = (const float*)d_in[5];
  const float* gate_w = (const float*)d_in[6];
  const float* gate_b = (const float*)d_in[7];
  const float* hc_w1  = (const float*)d_in[8];
  const float* hc_b1  = (const float*)d_in[9];
  const float* hc_g   = (const float*)d_in[10];
  const float* hc_be  = (const float*)d_in[11];
  const float* hc_w2  = (const float*)d_in[12];
  const float* hc_b2  = (const float*)d_in[13];
  const float* hc_aw  = (const float*)d_in[14];
  const float* hc_ab  = (const float*)d_in[15];
  const float* basis  = (const float*)d_in[16];
  const float* q_w    = (const float*)d_in[17];
  const float* q_b    = (const float*)d_in[18];
  const float* k_w    = (const float*)d_in[19];
  const float* k_b    = (const float*)d_in[20];
  const float* W_out  = (const float*)d_in[21];
  const float* b_out  = (const float*)d_in[22];

  float*  ws  = (float*)d_ws;
  float*  out = (float*)d_out;
  const int nB = in_sizes[0] / NF;

  setup_k<<<1, 128, 0, stream>>>(We, be_, adjw, Ww, hc_w1, hc_b1,
                                 basis, q_w, q_b, k_w, k_b, W_out, ws);

  const int blocks = (nB + 255) / 256;
  pass1_k<<<blocks, 256, 0, stream>>>(x, ws, Ww, hc_w1, hc_g, hc_be,
                                      hc_w2, hc_b2, hc_aw, hc_ab,
                                      (double*)(ws + WS_ACC), nB);
  pass2_k<<<blocks, 256, 0, stream>>>(x, ws, Vw, gate_w, gate_b, basis,
                                      b_out, (const double*)(ws + WS_ACC),
                                      out, nB);
}